// Round 1
// baseline (955.736 us; speedup 1.0000x reference)
//
#include <hip/hip_runtime.h>
#include <stdint.h>

#define NN 8192
#define DD 256
#define KK 32

// ---- order-preserving float -> u32 key; NaN canonicalized above +inf
// (numpy/jax sort NaNs to the end; ties then broken by index via low word)
__device__ __forceinline__ uint32_t sortable_key(float g) {
    if (g != g) return 0xFFFFFFFFu;
    uint32_t b = __float_as_uint(g);
    return (b & 0x80000000u) ? ~b : (b | 0x80000000u);
}

// insert into register-resident descending sorted array (static indexing only)
__device__ __forceinline__ void insert_desc(uint64_t (&top)[KK], uint64_t key) {
#pragma unroll
    for (int k = 0; k < KK; ++k) {
        uint64_t cur = top[k];
        bool gt = key > cur;
        uint64_t nw = gt ? key : cur;
        key = gt ? cur : key;
        top[k] = nw;
    }
}

// ---------------- K1: row sums s[i] = sum_f x[i,f]  (one wave per row)
__global__ __launch_bounds__(256) void k_rowsum(const float* __restrict__ x,
                                                float* __restrict__ s) {
    int row  = blockIdx.x * 4 + (threadIdx.x >> 6);
    int lane = threadIdx.x & 63;
    float4 v = reinterpret_cast<const float4*>(x)[(size_t)row * 64 + lane];
    float sum = (v.x + v.y) + (v.z + v.w);
#pragma unroll
    for (int off = 1; off < 64; off <<= 1) sum += __shfl_xor(sum, off, 64);
    if (lane == 0) s[row] = sum;
}

// ---------------- K2: fused dist/probs write + per-column segment top-K
// thread owns column j; block covers 256 columns x segr rows.
// cand layout: cand[(seg*K + k)*N + j]  (coalesced write & merge read)
__global__ __launch_bounds__(256) void k_fused(const float* __restrict__ q,
                                               const float* __restrict__ s,
                                               const float* __restrict__ tptr,
                                               float* __restrict__ dist_out,
                                               float* __restrict__ probs_out,
                                               uint64_t* __restrict__ cand,
                                               int segr) {
    const int j = blockIdx.x * 256 + threadIdx.x;
    const float sj = s[j];
    const float temp = tptr[0];

    uint64_t top[KK];
#pragma unroll
    for (int k = 0; k < KK; ++k) top[k] = 0;  // real keys are always > 0

    const int i0 = blockIdx.y * segr;
    for (int r = 0; r < segr; r += 4) {
        const int i = i0 + r;
        float qv[4], si[4];
#pragma unroll
        for (int u = 0; u < 4; ++u) qv[u] = q[(size_t)(i + u) * NN + j];
#pragma unroll
        for (int u = 0; u < 4; ++u) si[u] = s[i + u];  // wave-uniform -> scalar loads
#pragma unroll
        for (int u = 0; u < 4; ++u) {
            float diff = sj - si[u];
            float d = diff * diff;
            float pr = expf(-(temp * d)) + 1e-6f;          // probs (ref op order)
            dist_out[(size_t)(i + u) * NN + j]  = d;
            probs_out[(size_t)(i + u) * NN + j] = pr;
            float a = logf(pr + 1e-6f);
            float b = logf(-logf(qv[u] + 1e-6f));
            float g = a - b;
            uint64_t key = ((uint64_t)sortable_key(g) << 32) | (uint32_t)(i + u);
            if (key > top[KK - 1]) insert_desc(top, key);
        }
    }
    const size_t base = (size_t)blockIdx.y * KK * NN + j;
#pragma unroll
    for (int k = 0; k < KK; ++k) cand[base + (size_t)k * NN] = top[k];
}

// ---------------- K3: merge nseg segment lists -> 4 lists per column
__global__ __launch_bounds__(256) void k_merge1(const uint64_t* __restrict__ src,
                                                uint64_t* __restrict__ dst,
                                                int lists_per_grp) {
    int gid = blockIdx.x * 256 + threadIdx.x;
    int j   = gid & (NN - 1);
    int grp = gid >> 13;  // N = 8192
    uint64_t top[KK];
#pragma unroll
    for (int k = 0; k < KK; ++k) top[k] = 0;
    const int m0 = grp * lists_per_grp * KK;
    const int mc = lists_per_grp * KK;
    for (int m = 0; m < mc; ++m) {
        uint64_t key = src[(size_t)(m0 + m) * NN + j];
        if (key > top[KK - 1]) insert_desc(top, key);
    }
    const size_t base = (size_t)grp * KK * NN + j;
#pragma unroll
    for (int k = 0; k < KK; ++k) dst[base + (size_t)k * NN] = top[k];
}

// ---------------- K4: final merge of 4 lists + emit edges/weights/mask ones
__global__ __launch_bounds__(256) void k_final(const uint64_t* __restrict__ src,
                                               float* __restrict__ out) {
    const int j = blockIdx.x * 256 + threadIdx.x;
    uint64_t top[KK];
#pragma unroll
    for (int k = 0; k < KK; ++k) top[k] = 0;
    for (int m = 0; m < 4 * KK; ++m) {
        uint64_t key = src[(size_t)m * NN + j];
        if (key > top[KK - 1]) insert_desc(top, key);
    }
    const size_t KN = (size_t)KK * NN;
    float* child  = out;
    float* parent = out + KN;
    float* wts    = out + 2 * KN;
    float* mask   = out + 3 * KN + (size_t)NN * NN;   // after probs
#pragma unroll
    for (int k = 0; k < KK; ++k) {
        // rank (N-K+k) ascending == (K-1-k)-th in descending list
        uint32_t c = (uint32_t)top[KK - 1 - k];
        child [(size_t)k * NN + j] = (float)c;
        parent[(size_t)k * NN + j] = (float)j;
        wts   [(size_t)k * NN + j] = 1.0f;
        mask[(size_t)c * NN + j] = 1.0f;
        mask[(size_t)j * NN + c] = 1.0f;
    }
}

extern "C" void kernel_launch(void* const* d_in, const int* in_sizes, int n_in,
                              void* d_out, int out_size, void* d_ws, size_t ws_size,
                              hipStream_t stream) {
    const float* x    = (const float*)d_in[0];
    const float* q    = (const float*)d_in[1];
    const float* tptr = (const float*)d_in[2];
    float* out = (float*)d_out;

    const size_t KN = (size_t)KK * NN;
    float* probs_out = out + 3 * KN;
    float* mask_out  = out + 3 * KN + (size_t)NN * NN;
    float* dist_out  = out + 3 * KN + 2 * (size_t)NN * NN;

    // workspace: s[N] | cand0[N*nseg*K u64] | cand1[N*4*K u64]
    float* s = (float*)d_ws;
    const size_t cand1_bytes = (size_t)NN * 4 * KK * 8;
    int nseg = 32;
    while (nseg > 8 &&
           ws_size < 65536 + (size_t)NN * nseg * KK * 8 + cand1_bytes)
        nseg >>= 1;
    uint64_t* cand0 = (uint64_t*)((char*)d_ws + 65536);
    uint64_t* cand1 = cand0 + (size_t)NN * nseg * KK;
    const int segr = NN / nseg;

    k_rowsum<<<NN / 4, 256, 0, stream>>>(x, s);
    k_fused<<<dim3(NN / 256, nseg), 256, 0, stream>>>(q, s, tptr, dist_out,
                                                      probs_out, cand0, segr);
    (void)hipMemsetAsync(mask_out, 0, (size_t)NN * NN * sizeof(float), stream);
    k_merge1<<<(NN * 4) / 256, 256, 0, stream>>>(cand0, cand1, nseg / 4);
    k_final<<<NN / 256, 256, 0, stream>>>(cand1, out);
}

// Round 2
// 386.599 us; speedup vs baseline: 2.4722x; 2.4722x over previous
//
#include <hip/hip_runtime.h>
#include <stdint.h>

typedef unsigned long long ull;
#define NN 8192
#define KK 32

// order-preserving float->u32 key. Positive NaN (canonical on AMD) maps above
// +inf automatically, matching numpy/jax "NaNs sort last" + [-K:] selection.
__device__ __forceinline__ ull make_key(float g, int idx) {
    uint32_t b = __float_as_uint(g);
    uint32_t k = b ^ (0x80000000u | (uint32_t)((int32_t)b >> 31));
    return ((ull)k << 32) | (uint32_t)idx;
}

__device__ __forceinline__ void cas_both(ull &a, ull &b) {  // a >= b after
    ull x = a, y = b;
    bool g = x < y;
    a = g ? y : x;
    b = g ? x : y;
}

// full bitonic sort, descending, 16 u64 in registers (static indexing only)
__device__ __forceinline__ void sort16_desc(ull (&c)[16]) {
#pragma unroll
    for (int k = 2; k <= 16; k <<= 1) {
#pragma unroll
        for (int j = k >> 1; j > 0; j >>= 1) {
#pragma unroll
            for (int i = 0; i < 16; ++i) {
                int l = i ^ j;
                if (l > i) {
                    if ((i & k) == 0) cas_both(c[i], c[l]);  // descending run
                    else              cas_both(c[l], c[i]);  // ascending run
                }
            }
        }
    }
}

// bitonic merge of a 32-element bitonic sequence -> fully descending
__device__ __forceinline__ void bmerge32_desc(ull (&c)[32]) {
#pragma unroll
    for (int j = 16; j > 0; j >>= 1) {
#pragma unroll
        for (int i = 0; i < 32; ++i) {
            if ((i & j) == 0) cas_both(c[i], c[i ^ j]);
        }
    }
}

// merge sorted-desc ch[32] into sorted-desc acc[32], keeping top-32
__device__ __forceinline__ void merge_into32(ull (&acc)[32], const ull (&ch)[32]) {
#pragma unroll
    for (int k = 0; k < 32; ++k) {
        ull a = acc[31 - k], b = ch[k];
        acc[31 - k] = a >= b ? a : b;  // pointwise max(desc, asc) -> bitonic
    }
    bmerge32_desc(acc);
}

__device__ __forceinline__ void load_list32(const ull* __restrict__ src, int list,
                                            int j, ull (&ch)[32]) {
#pragma unroll
    for (int k = 0; k < 32; ++k)
        ch[k] = src[((size_t)list * 32 + k) * NN + j];
}

// ---------------- K1: row sums s[i] = sum_f x[i,f]
__global__ __launch_bounds__(256) void k_rowsum(const float* __restrict__ x,
                                                float* __restrict__ s) {
    int row  = blockIdx.x * 4 + (threadIdx.x >> 6);
    int lane = threadIdx.x & 63;
    float4 v = reinterpret_cast<const float4*>(x)[(size_t)row * 64 + lane];
    float sum = (v.x + v.y) + (v.z + v.w);
#pragma unroll
    for (int off = 1; off < 64; off <<= 1) sum += __shfl_xor(sum, off, 64);
    if (lane == 0) s[row] = sum;
}

// ---------------- K2: fused dist/probs write + per-column segment top-K
// thread owns column j; branch-free chunked sorting-network selection.
__global__ __launch_bounds__(256, 2) void k_fused(const float* __restrict__ q,
                                                  const float* __restrict__ s,
                                                  const float* __restrict__ tptr,
                                                  float* __restrict__ dist_out,
                                                  float* __restrict__ probs_out,
                                                  ull* __restrict__ cand,
                                                  int segr) {
    const int j = blockIdx.x * 256 + threadIdx.x;
    const float sj = s[j];
    const float temp = tptr[0];

    ull top[32];
#pragma unroll
    for (int k = 0; k < 32; ++k) top[k] = 0;  // real keys always > 0

    const int i0 = blockIdx.y * segr;
    for (int r = 0; r < segr; r += 16) {
        float qv[16];
#pragma unroll
        for (int u = 0; u < 16; ++u)
            qv[u] = q[(size_t)(i0 + r + u) * NN + j];

        ull ch[16];
#pragma unroll
        for (int u = 0; u < 16; ++u) {
            const int i = i0 + r + u;
            float diff = sj - s[i];            // s[i] wave-uniform -> scalar load
            float d = diff * diff;
            float pr = expf(-(temp * d)) + 1e-6f;  // probs, ref op order
            size_t off = (size_t)i * NN + j;
            dist_out[off]  = d;
            probs_out[off] = pr;
            float a = logf(pr + 1e-6f);
            float b = logf(-logf(qv[u] + 1e-6f));
            ch[u] = make_key(a - b, i);
        }
        sort16_desc(ch);
        // cross step: pair top[16+u] (desc) with ch[15-u] (asc), keep max.
#pragma unroll
        for (int u = 0; u < 16; ++u) {
            ull a = top[16 + u], b = ch[15 - u];
            top[16 + u] = a >= b ? a : b;
        }
        bmerge32_desc(top);  // prefix desc + bitonic tail => bitonic overall
    }
    const size_t base = (size_t)blockIdx.y * KK * NN + j;
#pragma unroll
    for (int k = 0; k < KK; ++k) cand[base + (size_t)k * NN] = top[k];
}

// ---------------- K3: merge 4 sorted segment lists -> 1 sorted list
__global__ __launch_bounds__(256) void k_merge1(const ull* __restrict__ src,
                                                ull* __restrict__ dst) {
    int gid = blockIdx.x * 256 + threadIdx.x;
    int j   = gid & (NN - 1);
    int grp = gid >> 13;  // 0..3
    ull acc[32];
    load_list32(src, grp * 4, j, acc);
#pragma unroll
    for (int l = 1; l < 4; ++l) {
        ull ch[32];
        load_list32(src, grp * 4 + l, j, ch);
        merge_into32(acc, ch);
    }
    const size_t base = (size_t)grp * KK * NN + j;
#pragma unroll
    for (int k = 0; k < KK; ++k) dst[base + (size_t)k * NN] = acc[k];
}

// ---------------- K4: final merge of 4 lists + emit edges/weights/mask ones
__global__ __launch_bounds__(256) void k_final(const ull* __restrict__ src,
                                               float* __restrict__ out) {
    const int j = blockIdx.x * 256 + threadIdx.x;
    ull acc[32];
    load_list32(src, 0, j, acc);
#pragma unroll
    for (int l = 1; l < 4; ++l) {
        ull ch[32];
        load_list32(src, l, j, ch);
        merge_into32(acc, ch);
    }
    const size_t KN = (size_t)KK * NN;
    float* child  = out;
    float* parent = out + KN;
    float* wts    = out + 2 * KN;
    float* mask   = out + 3 * KN + (size_t)NN * NN;  // after probs
#pragma unroll
    for (int k = 0; k < KK; ++k) {
        // ascending rank (N-K+k) == descending rank (K-1-k)
        uint32_t c = (uint32_t)acc[KK - 1 - k];
        child [(size_t)k * NN + j] = (float)c;
        parent[(size_t)k * NN + j] = (float)j;
        wts   [(size_t)k * NN + j] = 1.0f;
        mask[(size_t)c * NN + j] = 1.0f;
        mask[(size_t)j * NN + c] = 1.0f;
    }
}

extern "C" void kernel_launch(void* const* d_in, const int* in_sizes, int n_in,
                              void* d_out, int out_size, void* d_ws, size_t ws_size,
                              hipStream_t stream) {
    const float* x    = (const float*)d_in[0];
    const float* q    = (const float*)d_in[1];
    const float* tptr = (const float*)d_in[2];
    float* out = (float*)d_out;

    const size_t KN = (size_t)KK * NN;
    float* probs_out = out + 3 * KN;
    float* mask_out  = out + 3 * KN + (size_t)NN * NN;
    float* dist_out  = out + 3 * KN + 2 * (size_t)NN * NN;

    // workspace: s[N] | cand0[16 lists] | cand1[4 lists]   (~42 MB)
    const int nseg = 16;
    const int segr = NN / nseg;  // 512
    float* s = (float*)d_ws;
    ull* cand0 = (ull*)((char*)d_ws + 65536);
    ull* cand1 = cand0 + (size_t)NN * nseg * KK;

    k_rowsum<<<NN / 4, 256, 0, stream>>>(x, s);
    k_fused<<<dim3(NN / 256, nseg), 256, 0, stream>>>(q, s, tptr, dist_out,
                                                      probs_out, cand0, segr);
    (void)hipMemsetAsync(mask_out, 0, (size_t)NN * NN * sizeof(float), stream);
    k_merge1<<<(NN * 4) / 256, 256, 0, stream>>>(cand0, cand1);
    k_final<<<NN / 256, 256, 0, stream>>>(cand1, out);
}

// Round 3
// 363.171 us; speedup vs baseline: 2.6316x; 1.0645x over previous
//
#include <hip/hip_runtime.h>
#include <stdint.h>

typedef unsigned long long ull;
#define NN 8192
#define KK 32

// order-preserving float->u32 key. Positive NaN (canonical on AMD) maps above
// +inf automatically, matching numpy/jax "NaNs sort last" + [-K:] selection.
__device__ __forceinline__ ull make_key(float g, int idx) {
    uint32_t b = __float_as_uint(g);
    uint32_t k = b ^ (0x80000000u | (uint32_t)((int32_t)b >> 31));
    return ((ull)k << 32) | (uint32_t)idx;
}

__device__ __forceinline__ void cas_both(ull &a, ull &b) {  // a >= b after
    ull x = a, y = b;
    bool g = x < y;
    a = g ? y : x;
    b = g ? x : y;
}

// full bitonic sort, descending, 16 u64 in registers (static indexing only)
__device__ __forceinline__ void sort16_desc(ull (&c)[16]) {
#pragma unroll
    for (int k = 2; k <= 16; k <<= 1) {
#pragma unroll
        for (int j = k >> 1; j > 0; j >>= 1) {
#pragma unroll
            for (int i = 0; i < 16; ++i) {
                int l = i ^ j;
                if (l > i) {
                    if ((i & k) == 0) cas_both(c[i], c[l]);  // descending run
                    else              cas_both(c[l], c[i]);  // ascending run
                }
            }
        }
    }
}

// bitonic merge of a 32-element bitonic sequence -> fully descending
__device__ __forceinline__ void bmerge32_desc(ull (&c)[32]) {
#pragma unroll
    for (int j = 16; j > 0; j >>= 1) {
#pragma unroll
        for (int i = 0; i < 32; ++i) {
            if ((i & j) == 0) cas_both(c[i], c[i ^ j]);
        }
    }
}

// merge sorted-desc ch[32] into sorted-desc acc[32], keeping top-32
__device__ __forceinline__ void merge_into32(ull (&acc)[32], const ull (&ch)[32]) {
#pragma unroll
    for (int k = 0; k < 32; ++k) {
        ull a = acc[31 - k], b = ch[k];
        acc[31 - k] = a >= b ? a : b;  // pointwise max(desc, rev-desc) -> bitonic
    }
    bmerge32_desc(acc);
}

__device__ __forceinline__ void load_list32(const ull* __restrict__ src, int list,
                                            int j, ull (&ch)[32]) {
#pragma unroll
    for (int k = 0; k < 32; ++k)
        ch[k] = src[((size_t)list * 32 + k) * NN + j];
}

// ---------------- K1: row sums s[i] = sum_f x[i,f]
__global__ __launch_bounds__(256) void k_rowsum(const float* __restrict__ x,
                                                float* __restrict__ s) {
    int row  = blockIdx.x * 4 + (threadIdx.x >> 6);
    int lane = threadIdx.x & 63;
    float4 v = reinterpret_cast<const float4*>(x)[(size_t)row * 64 + lane];
    float sum = (v.x + v.y) + (v.z + v.w);
#pragma unroll
    for (int off = 1; off < 64; off <<= 1) sum += __shfl_xor(sum, off, 64);
    if (lane == 0) s[row] = sum;
}

// ---------------- K2: fused dist/probs write + per-column segment top-K
// + interleaved zeroing of the mask output (replaces the serial memset).
// thread owns column j; branch-free chunked sorting-network selection.
__global__ __launch_bounds__(256, 2) void k_fused(const float* __restrict__ q,
                                                  const float* __restrict__ s,
                                                  const float* __restrict__ tptr,
                                                  float* __restrict__ dist_out,
                                                  float* __restrict__ probs_out,
                                                  float4* __restrict__ mask4,
                                                  ull* __restrict__ cand,
                                                  int segr) {
    const int j = blockIdx.x * 256 + threadIdx.x;
    const int gtid = (blockIdx.y * (NN / 256) + blockIdx.x) * 256 + threadIdx.x;
    const float sj = s[j];
    const float temp = tptr[0];
    const float4 z4 = make_float4(0.f, 0.f, 0.f, 0.f);

    ull top[32];
#pragma unroll
    for (int k = 0; k < 32; ++k) top[k] = 0;  // real keys always > 0

    const int i0 = blockIdx.y * segr;
    for (int r = 0; r < segr; r += 16) {
        const int it = r >> 4;  // 0..31 (segr = 512)
        float qv[16];
#pragma unroll
        for (int u = 0; u < 16; ++u)
            qv[u] = q[(size_t)(i0 + r + u) * NN + j];

        ull ch[16];
#pragma unroll
        for (int u = 0; u < 16; ++u) {
            const int i = i0 + r + u;
            float diff = sj - s[i];            // s[i] wave-uniform -> scalar load
            float d = diff * diff;
            float pr = expf(-(temp * d)) + 1e-6f;  // probs, ref op order
            size_t off = (size_t)i * NN + j;
            dist_out[off]  = d;
            probs_out[off] = pr;
            float a = logf(pr + 1e-6f);
            float b = logf(-logf(qv[u] + 1e-6f));
            ch[u] = make_key(a - b, i);
        }
        // interleaved mask zeroing: 4 coalesced float4 stores per chunk
        // (131072 threads x 32 iters x 4 = 16Mi float4 = 64Mi floats = NN*NN)
#pragma unroll
        for (int u = 0; u < 4; ++u)
            mask4[(size_t)(it * 4 + u) * (128 * 1024) + gtid] = z4;

        sort16_desc(ch);
        // cross step: pair top[16+u] (desc) with ch[15-u] (asc), keep max.
#pragma unroll
        for (int u = 0; u < 16; ++u) {
            ull a = top[16 + u], b = ch[15 - u];
            top[16 + u] = a >= b ? a : b;
        }
        bmerge32_desc(top);  // prefix desc + bitonic tail => bitonic overall
    }
    const size_t base = (size_t)blockIdx.y * KK * NN + j;
#pragma unroll
    for (int k = 0; k < KK; ++k) cand[base + (size_t)k * NN] = top[k];
}

// ---------------- K3: merge 16 sorted segment lists -> 4 per column
__global__ __launch_bounds__(256) void k_merge1(const ull* __restrict__ src,
                                                ull* __restrict__ dst) {
    int gid = blockIdx.x * 256 + threadIdx.x;
    int j   = gid & (NN - 1);
    int grp = gid >> 13;  // 0..3
    ull acc[32];
    load_list32(src, grp * 4, j, acc);
#pragma unroll
    for (int l = 1; l < 4; ++l) {
        ull ch[32];
        load_list32(src, grp * 4 + l, j, ch);
        merge_into32(acc, ch);
    }
    const size_t base = (size_t)grp * KK * NN + j;
#pragma unroll
    for (int k = 0; k < KK; ++k) dst[base + (size_t)k * NN] = acc[k];
}

// ---------------- K4: final merge of 4 lists + emit edges/weights
__global__ __launch_bounds__(64) void k_final(const ull* __restrict__ src,
                                              float* __restrict__ out) {
    const int j = blockIdx.x * 64 + threadIdx.x;
    ull acc[32];
    load_list32(src, 0, j, acc);
#pragma unroll
    for (int l = 1; l < 4; ++l) {
        ull ch[32];
        load_list32(src, l, j, ch);
        merge_into32(acc, ch);
    }
    const size_t KN = (size_t)KK * NN;
    float* child  = out;
    float* parent = out + KN;
    float* wts    = out + 2 * KN;
#pragma unroll
    for (int k = 0; k < KK; ++k) {
        // ascending rank (N-K+k) == descending rank (K-1-k)
        uint32_t c = (uint32_t)acc[KK - 1 - k];
        child [(size_t)k * NN + j] = (float)c;
        parent[(size_t)k * NN + j] = (float)j;
        wts   [(size_t)k * NN + j] = 1.0f;
    }
}

// ---------------- K5: symmetric scatter of ones into mask (max parallelism)
__global__ __launch_bounds__(256) void k_scatter(const float* __restrict__ child,
                                                 float* __restrict__ mask) {
    int gid = blockIdx.x * 256 + threadIdx.x;  // 0 .. K*N-1
    int j = gid & (NN - 1);
    int k = gid >> 13;
    uint32_t c = (uint32_t)child[(size_t)k * NN + j];
    mask[(size_t)c * NN + j] = 1.0f;
    mask[(size_t)j * NN + c] = 1.0f;
}

extern "C" void kernel_launch(void* const* d_in, const int* in_sizes, int n_in,
                              void* d_out, int out_size, void* d_ws, size_t ws_size,
                              hipStream_t stream) {
    const float* x    = (const float*)d_in[0];
    const float* q    = (const float*)d_in[1];
    const float* tptr = (const float*)d_in[2];
    float* out = (float*)d_out;

    const size_t KN = (size_t)KK * NN;
    float* probs_out = out + 3 * KN;
    float* mask_out  = out + 3 * KN + (size_t)NN * NN;
    float* dist_out  = out + 3 * KN + 2 * (size_t)NN * NN;

    // workspace: s[N] | cand0[16 lists] | cand1[4 lists]   (~42 MB)
    const int nseg = 16;
    const int segr = NN / nseg;  // 512
    float* s = (float*)d_ws;
    ull* cand0 = (ull*)((char*)d_ws + 65536);
    ull* cand1 = cand0 + (size_t)NN * nseg * KK;

    k_rowsum<<<NN / 4, 256, 0, stream>>>(x, s);
    k_fused<<<dim3(NN / 256, nseg), 256, 0, stream>>>(
        q, s, tptr, dist_out, probs_out, (float4*)mask_out, cand0, segr);
    k_merge1<<<(NN * 4) / 256, 256, 0, stream>>>(cand0, cand1);
    k_final<<<NN / 64, 64, 0, stream>>>(cand1, out);
    k_scatter<<<(KK * NN) / 256, 256, 0, stream>>>(out, mask_out);
}